// Round 1
// baseline (1097.781 us; speedup 1.0000x reference)
//
#include <hip/hip_runtime.h>

// Sequence: 2-layer LSTM (H=12) over T=1024 steps + 64 free-running steps.
// Layout: 16 lanes per batch element; lane k (k<12) owns hidden unit k and
// holds all weight rows touching unit k in VGPRs (~158 floats). h1/h2 are
// broadcast within the 16-lane group each step via ds_swizzle (no LDS, no
// barriers). Linear head = xor-swizzle reduction over the 16-lane group.

constexpr int H   = 12;
constexpr int T   = 1024;
constexpr int FUT = 64;
constexpr int TT  = T + FUT;   // 1088
constexpr int B   = 8192;

// ds_swizzle BitMode: src_lane = ((lane & and) | or) ^ xor, within 32-lane half.
// Broadcast lane J within 16-group: and=0x10 (keep bit4), or=J, xor=0.
#define SWZB(v, J)  __int_as_float(__builtin_amdgcn_ds_swizzle(__float_as_int(v), (((J) << 5) | 0x10)))
// Butterfly xor within 16-group: and=0x1f, or=0, xor=M (M in {1,2,4,8}).
#define SWZX(v, M)  __int_as_float(__builtin_amdgcn_ds_swizzle(__float_as_int(v), (((M) << 10) | 0x1f)))

#define BC12(dst, v) do { \
  dst[0] = SWZB(v, 0);   dst[1] = SWZB(v, 1);   dst[2] = SWZB(v, 2); \
  dst[3] = SWZB(v, 3);   dst[4] = SWZB(v, 4);   dst[5] = SWZB(v, 5); \
  dst[6] = SWZB(v, 6);   dst[7] = SWZB(v, 7);   dst[8] = SWZB(v, 8); \
  dst[9] = SWZB(v, 9);   dst[10] = SWZB(v, 10); dst[11] = SWZB(v, 11); \
} while (0)

static __device__ __forceinline__ float fexp2(float x) {
#if __has_builtin(__builtin_amdgcn_exp2f)
  return __builtin_amdgcn_exp2f(x);
#else
  return __exp2f(x);
#endif
}

static __device__ __forceinline__ float frcp(float x) {
#if __has_builtin(__builtin_amdgcn_rcpf)
  return __builtin_amdgcn_rcpf(x);
#else
  return 1.0f / x;
#endif
}

// sigmoid(x) = 1 / (1 + exp(-x)); exp(-x) = 2^(-x*log2e)
static __device__ __forceinline__ float sigf(float x) {
  return frcp(1.0f + fexp2(-1.442695040888963f * x));
}

// tanh(x) = 1 - 2/(exp(2x)+1); exp(2x) = 2^(x*2*log2e)
// Saturates correctly: exp2(+inf)->inf, rcp(inf)->0 -> 1; exp2(-big)->0 -> -1.
static __device__ __forceinline__ float tanhf_fast(float x) {
  return 1.0f - 2.0f * frcp(1.0f + fexp2(2.885390081777927f * x));
}

__global__ __launch_bounds__(256, 2) void lstm_seq_kernel(
    const float* __restrict__ input,
    const float* __restrict__ w_ih1, const float* __restrict__ w_hh1,
    const float* __restrict__ b_ih1, const float* __restrict__ b_hh1,
    const float* __restrict__ w_ih2, const float* __restrict__ w_hh2,
    const float* __restrict__ b_ih2, const float* __restrict__ b_hh2,
    const float* __restrict__ w_lin, const float* __restrict__ b_lin,
    float* __restrict__ out)
{
  const int lane16 = threadIdx.x & 15;
  const int k      = (lane16 < H) ? lane16 : (H - 1);   // clamp idle lanes
  const int e      = blockIdx.x * 16 + (threadIdx.x >> 4);

  // ---- load per-unit weight slices into registers (amortized over 1088 steps)
  // PyTorch gate order along the 4H axis: i, f, g, o -> row = q*H + k.
  float wi1[4], b1c[4], b2c[4];
  float wh1[4][H], wi2[4][H], wh2[4][H];
  #pragma unroll
  for (int q = 0; q < 4; ++q) {
    const int row = q * H + k;
    wi1[q] = w_ih1[row];                    // w_ih1 is [48,1]
    b1c[q] = b_ih1[row] + b_hh1[row];
    b2c[q] = b_ih2[row] + b_hh2[row];
    #pragma unroll
    for (int j = 0; j < H; ++j) {
      wh1[q][j] = w_hh1[row * H + j];
      wi2[q][j] = w_ih2[row * H + j];
      wh2[q][j] = w_hh2[row * H + j];
    }
  }
  const float wlin = (lane16 < H) ? w_lin[k] : 0.0f;    // zero so idle lanes drop out of reduction
  const float blin = b_lin[0];

  // ---- state
  float h1[H], h2[H];
  #pragma unroll
  for (int j = 0; j < H; ++j) { h1[j] = 0.0f; h2[j] = 0.0f; }
  float c1 = 0.0f, c2 = 0.0f;

  const float* xrow = input + (size_t)e * T;
  float*       yrow = out   + (size_t)e * TT;

  auto step = [&](float x) -> float {
    // cell 1: gates for unit k (i,f,g,o)
    float g1[4];
    #pragma unroll
    for (int q = 0; q < 4; ++q) {
      float a = b1c[q] + wi1[q] * x;
      #pragma unroll
      for (int j = 0; j < H; ++j) a += wh1[q][j] * h1[j];
      g1[q] = a;
    }
    const float i1 = sigf(g1[0]);
    const float f1 = sigf(g1[1]);
    const float g1g = tanhf_fast(g1[2]);
    const float o1 = sigf(g1[3]);
    c1 = f1 * c1 + i1 * g1g;
    const float h1o = o1 * tanhf_fast(c1);
    BC12(h1, h1o);   // broadcast new h1 across the 16-lane group

    // cell 2
    float g2[4];
    #pragma unroll
    for (int q = 0; q < 4; ++q) {
      float a = b2c[q];
      #pragma unroll
      for (int j = 0; j < H; ++j) a += wi2[q][j] * h1[j];
      #pragma unroll
      for (int j = 0; j < H; ++j) a += wh2[q][j] * h2[j];
      g2[q] = a;
    }
    const float i2 = sigf(g2[0]);
    const float f2 = sigf(g2[1]);
    const float g2g = tanhf_fast(g2[2]);
    const float o2 = sigf(g2[3]);
    c2 = f2 * c2 + i2 * g2g;
    const float h2o = o2 * tanhf_fast(c2);
    BC12(h2, h2o);

    // y = sum_k wlin[k]*h2[k] + blin (xor-butterfly over the 16-lane group;
    // idle lanes contribute 0 via wlin=0)
    float p = wlin * h2o;
    p += SWZX(p, 1);
    p += SWZX(p, 2);
    p += SWZX(p, 4);
    p += SWZX(p, 8);
    return p + blin;
  };

  // main sequence: 4-step unroll, float4 input load / float4 output store
  for (int tb = 0; tb < T; tb += 4) {
    const float4 xv = *reinterpret_cast<const float4*>(xrow + tb);
    float y0 = step(xv.x);
    float y1 = step(xv.y);
    float y2 = step(xv.z);
    float y3 = step(xv.w);
    if (lane16 == 0)
      *reinterpret_cast<float4*>(yrow + tb) = make_float4(y0, y1, y2, y3);
  }

  // free-running: keep feeding the last input sample
  const float xl = xrow[T - 1];
  for (int tb = T; tb < TT; tb += 4) {
    float y0 = step(xl);
    float y1 = step(xl);
    float y2 = step(xl);
    float y3 = step(xl);
    if (lane16 == 0)
      *reinterpret_cast<float4*>(yrow + tb) = make_float4(y0, y1, y2, y3);
  }
}

extern "C" void kernel_launch(void* const* d_in, const int* in_sizes, int n_in,
                              void* d_out, int out_size, void* d_ws, size_t ws_size,
                              hipStream_t stream) {
  const float* input = (const float*)d_in[0];
  // d_in[1] = future (scalar int, hardcoded 64 to match the harness)
  const float* w_ih1 = (const float*)d_in[2];
  const float* w_hh1 = (const float*)d_in[3];
  const float* b_ih1 = (const float*)d_in[4];
  const float* b_hh1 = (const float*)d_in[5];
  const float* w_ih2 = (const float*)d_in[6];
  const float* w_hh2 = (const float*)d_in[7];
  const float* b_ih2 = (const float*)d_in[8];
  const float* b_hh2 = (const float*)d_in[9];
  const float* w_lin = (const float*)d_in[10];
  const float* b_lin = (const float*)d_in[11];
  float* out = (float*)d_out;

  dim3 grid(B / 16);   // 16 elements per 256-thread block
  dim3 block(256);
  hipLaunchKernelGGL(lstm_seq_kernel, grid, block, 0, stream,
                     input, w_ih1, w_hh1, b_ih1, b_hh1,
                     w_ih2, w_hh2, b_ih2, b_hh2, w_lin, b_lin, out);
}

// Round 2
// 851.840 us; speedup vs baseline: 1.2887x; 1.2887x over previous
//
#include <hip/hip_runtime.h>

// 2-layer LSTM (H=12), B=8192, T=1024 + 64 free-running steps.
// 16 lanes per element; lane k owns hidden unit k (both cells).
// Hidden-state dot products packed along j via v_pk_fma_f32 (h and weights
// stored as float2 {.[2m], .[2m+1]}). All cross-lane traffic via DPP
// (row_newbcast for h broadcast, quad_perm/row_shl butterfly for y-reduce):
// zero LDS, zero lgkmcnt. Weights prescaled by +-log2e so exp2 args are ready.

constexpr int H   = 12;
constexpr int T   = 1024;
constexpr int FUT = 64;
constexpr int TT  = T + FUT;   // 1088
constexpr int B   = 8192;
constexpr int HP  = H / 2;     // 6 packed j-pairs

// DPP: row_newbcast:J = 0x150+J (broadcast lane J within each 16-lane row)
#define BCAST(v, J) __int_as_float(__builtin_amdgcn_mov_dpp(__float_as_int(v), 0x150 + (J), 0xF, 0xF, false))
// generic DPP move with bound_ctrl=1 (out-of-range reads 0)
#define DPPMV(v, C) __int_as_float(__builtin_amdgcn_mov_dpp(__float_as_int(v), (C), 0xF, 0xF, true))

static __device__ __forceinline__ float2 pk_fma(float2 a, float2 b, float2 c) {
  float2 d;
  asm("v_pk_fma_f32 %0, %1, %2, %3" : "=v"(d) : "v"(a), "v"(b), "v"(c));
  return d;
}
static __device__ __forceinline__ float2 pk_mul(float2 a, float2 b) {
  float2 d;
  asm("v_pk_mul_f32 %0, %1, %2" : "=v"(d) : "v"(a), "v"(b));
  return d;
}

static __device__ __forceinline__ float fexp2(float x) {
  return __builtin_amdgcn_exp2f(x);
}
static __device__ __forceinline__ float frcp(float x) {
  return __builtin_amdgcn_rcpf(x);
}

// arg prescaled by -log2e:  sigmoid(x) = 1/(1+2^s), s = -x*log2e
static __device__ __forceinline__ float sig_pre(float s) {
  return frcp(1.0f + fexp2(s));
}
// arg prescaled by +2*log2e: tanh(x) = 1 - 2/(1+2^s), s = 2x*log2e
static __device__ __forceinline__ float tanh_pre(float s) {
  return fmaf(-2.0f, frcp(1.0f + fexp2(s)), 1.0f);
}
// unscaled arg (cell state)
static __device__ __forceinline__ float tanh_c(float x) {
  return fmaf(-2.0f, frcp(1.0f + fexp2(2.885390081777927f * x)), 1.0f);
}

__global__ __launch_bounds__(256, 2) void lstm_seq_kernel(
    const float* __restrict__ input,
    const float* __restrict__ w_ih1, const float* __restrict__ w_hh1,
    const float* __restrict__ b_ih1, const float* __restrict__ b_hh1,
    const float* __restrict__ w_ih2, const float* __restrict__ w_hh2,
    const float* __restrict__ b_ih2, const float* __restrict__ b_hh2,
    const float* __restrict__ w_lin, const float* __restrict__ b_lin,
    float* __restrict__ out)
{
  const int lane16 = threadIdx.x & 15;
  const int k      = (lane16 < H) ? lane16 : (H - 1);   // clamp idle lanes
  const int e      = blockIdx.x * 16 + (threadIdx.x >> 4);

  const float LOG2E = 1.4426950408889634f;
  // gate order i,f,g,o: sigmoid gates prescaled by -log2e, tanh gate by +2log2e
  const float sc[4] = { -LOG2E, -LOG2E, 2.0f * LOG2E, -LOG2E };

  float  wi1s[4], b1s[4], b2s[4];
  float2 wh1p[4][HP], wi2p[4][HP], wh2p[4][HP];
  #pragma unroll
  for (int q = 0; q < 4; ++q) {
    const int   row = q * H + k;
    const float s   = sc[q];
    wi1s[q] = w_ih1[row] * s;                 // w_ih1 is [48,1]
    b1s[q]  = (b_ih1[row] + b_hh1[row]) * s;
    b2s[q]  = (b_ih2[row] + b_hh2[row]) * s;
    #pragma unroll
    for (int m = 0; m < HP; ++m) {
      wh1p[q][m] = make_float2(w_hh1[row * H + 2*m] * s, w_hh1[row * H + 2*m + 1] * s);
      wi2p[q][m] = make_float2(w_ih2[row * H + 2*m] * s, w_ih2[row * H + 2*m + 1] * s);
      wh2p[q][m] = make_float2(w_hh2[row * H + 2*m] * s, w_hh2[row * H + 2*m + 1] * s);
    }
  }
  const float wlin = (lane16 < H) ? w_lin[k] : 0.0f;    // idle lanes drop out of reduce
  const float blin = b_lin[0];

  float2 h1p[HP], h2p[HP];
  #pragma unroll
  for (int m = 0; m < HP; ++m) { h1p[m] = make_float2(0.f, 0.f); h2p[m] = make_float2(0.f, 0.f); }
  float c1 = 0.0f, c2 = 0.0f;

  const float* xrow = input + (size_t)e * T;
  float*       yrow = out   + (size_t)e * TT;

  auto step = [&](float x) -> float {
    // ---- cell 1 gates (packed j-dot)
    float g1[4];
    #pragma unroll
    for (int q = 0; q < 4; ++q) {
      float2 a = pk_mul(h1p[0], wh1p[q][0]);
      #pragma unroll
      for (int m = 1; m < HP; ++m) a = pk_fma(h1p[m], wh1p[q][m], a);
      g1[q] = (a.x + a.y) + fmaf(wi1s[q], x, b1s[q]);
    }
    const float i1 = sig_pre(g1[0]);
    const float f1 = sig_pre(g1[1]);
    const float gg1 = tanh_pre(g1[2]);
    const float o1 = sig_pre(g1[3]);
    c1 = fmaf(f1, c1, i1 * gg1);
    const float h1o = o1 * tanh_c(c1);

    // broadcast new h1 across the 16-lane group (DPP, no LDS)
    h1p[0] = make_float2(BCAST(h1o, 0),  BCAST(h1o, 1));
    h1p[1] = make_float2(BCAST(h1o, 2),  BCAST(h1o, 3));
    h1p[2] = make_float2(BCAST(h1o, 4),  BCAST(h1o, 5));
    h1p[3] = make_float2(BCAST(h1o, 6),  BCAST(h1o, 7));
    h1p[4] = make_float2(BCAST(h1o, 8),  BCAST(h1o, 9));
    h1p[5] = make_float2(BCAST(h1o, 10), BCAST(h1o, 11));

    // ---- cell 2 gates (single packed chain over h1 and h2)
    float g2[4];
    #pragma unroll
    for (int q = 0; q < 4; ++q) {
      float2 a = pk_mul(h1p[0], wi2p[q][0]);
      #pragma unroll
      for (int m = 1; m < HP; ++m) a = pk_fma(h1p[m], wi2p[q][m], a);
      #pragma unroll
      for (int m = 0; m < HP; ++m) a = pk_fma(h2p[m], wh2p[q][m], a);
      g2[q] = (a.x + a.y) + b2s[q];
    }
    const float i2 = sig_pre(g2[0]);
    const float f2 = sig_pre(g2[1]);
    const float gg2 = tanh_pre(g2[2]);
    const float o2 = sig_pre(g2[3]);
    c2 = fmaf(f2, c2, i2 * gg2);
    const float h2o = o2 * tanh_c(c2);

    h2p[0] = make_float2(BCAST(h2o, 0),  BCAST(h2o, 1));
    h2p[1] = make_float2(BCAST(h2o, 2),  BCAST(h2o, 3));
    h2p[2] = make_float2(BCAST(h2o, 4),  BCAST(h2o, 5));
    h2p[3] = make_float2(BCAST(h2o, 6),  BCAST(h2o, 7));
    h2p[4] = make_float2(BCAST(h2o, 8),  BCAST(h2o, 9));
    h2p[5] = make_float2(BCAST(h2o, 10), BCAST(h2o, 11));

    // ---- y = w_lin . h2 + b (DPP butterfly within the 16-lane group)
    float p = wlin * h2o;
    p += DPPMV(p, 0xB1);   // quad_perm [1,0,3,2]  (xor 1)
    p += DPPMV(p, 0x4E);   // quad_perm [2,3,0,1]  (xor 2)
    p += DPPMV(p, 0x104);  // row_shl:4  -> lane i += lane i+4
    p += DPPMV(p, 0x108);  // row_shl:8  -> lane 0 has full sum
    return p + blin;
  };

  for (int tb = 0; tb < T; tb += 4) {
    const float4 xv = *reinterpret_cast<const float4*>(xrow + tb);
    float y0 = step(xv.x);
    float y1 = step(xv.y);
    float y2 = step(xv.z);
    float y3 = step(xv.w);
    if (lane16 == 0)
      *reinterpret_cast<float4*>(yrow + tb) = make_float4(y0, y1, y2, y3);
  }

  const float xl = xrow[T - 1];
  for (int tb = T; tb < TT; tb += 4) {
    float y0 = step(xl);
    float y1 = step(xl);
    float y2 = step(xl);
    float y3 = step(xl);
    if (lane16 == 0)
      *reinterpret_cast<float4*>(yrow + tb) = make_float4(y0, y1, y2, y3);
  }
}

extern "C" void kernel_launch(void* const* d_in, const int* in_sizes, int n_in,
                              void* d_out, int out_size, void* d_ws, size_t ws_size,
                              hipStream_t stream) {
  const float* input = (const float*)d_in[0];
  const float* w_ih1 = (const float*)d_in[2];
  const float* w_hh1 = (const float*)d_in[3];
  const float* b_ih1 = (const float*)d_in[4];
  const float* b_hh1 = (const float*)d_in[5];
  const float* w_ih2 = (const float*)d_in[6];
  const float* w_hh2 = (const float*)d_in[7];
  const float* b_ih2 = (const float*)d_in[8];
  const float* b_hh2 = (const float*)d_in[9];
  const float* w_lin = (const float*)d_in[10];
  const float* b_lin = (const float*)d_in[11];
  float* out = (float*)d_out;

  dim3 grid(B / 16);
  dim3 block(256);
  hipLaunchKernelGGL(lstm_seq_kernel, grid, block, 0, stream,
                     input, w_ih1, w_hh1, b_ih1, b_hh1,
                     w_ih2, w_hh2, b_ih2, b_hh2, w_lin, b_lin, out);
}

// Round 3
// 779.499 us; speedup vs baseline: 1.4083x; 1.0928x over previous
//
#include <hip/hip_runtime.h>

// 2-layer LSTM (H=12), B=8192, T=1024 + 64 free-running steps.
// 16 lanes per element; lane k owns hidden unit k (both cells).
// Dots packed via v_pk_fma_f32 (density), cross-lane via DPP only.
// Activations use merged-reciprocal algebra: 2 rcp per cell instead of 5:
//   sig(i)*tanh(g) and f*c fused over a common denominator,
//   sig(o)*tanh(c') fused over a common denominator.
// Biases pre-folded into pk accumulator init as const float2 pairs.
// Cell2's h2-partial dots are issued BEFORE the h1 broadcast to hide
// DPP hazard/latency.

constexpr int H   = 12;
constexpr int T   = 1024;
constexpr int FUT = 64;
constexpr int TT  = T + FUT;   // 1088
constexpr int B   = 8192;
constexpr int HP  = H / 2;     // 6 packed j-pairs

// DPP: row_newbcast:J = 0x150+J (broadcast lane J within each 16-lane row)
#define BCAST(v, J) __int_as_float(__builtin_amdgcn_mov_dpp(__float_as_int(v), 0x150 + (J), 0xF, 0xF, false))
// generic DPP move with bound_ctrl=1 (out-of-range reads 0)
#define DPPMV(v, C) __int_as_float(__builtin_amdgcn_mov_dpp(__float_as_int(v), (C), 0xF, 0xF, true))

static __device__ __forceinline__ float2 pk_fma(float2 a, float2 b, float2 c) {
  float2 d;
  asm("v_pk_fma_f32 %0, %1, %2, %3" : "=v"(d) : "v"(a), "v"(b), "v"(c));
  return d;
}

static __device__ __forceinline__ float fexp2(float x) {
  return __builtin_amdgcn_exp2f(x);
}
static __device__ __forceinline__ float frcp(float x) {
  return __builtin_amdgcn_rcpf(x);
}

__global__ __launch_bounds__(256, 2) void lstm_seq_kernel(
    const float* __restrict__ input,
    const float* __restrict__ w_ih1, const float* __restrict__ w_hh1,
    const float* __restrict__ b_ih1, const float* __restrict__ b_hh1,
    const float* __restrict__ w_ih2, const float* __restrict__ w_hh2,
    const float* __restrict__ b_ih2, const float* __restrict__ b_hh2,
    const float* __restrict__ w_lin, const float* __restrict__ b_lin,
    float* __restrict__ out)
{
  const int lane16 = threadIdx.x & 15;
  const int k      = (lane16 < H) ? lane16 : (H - 1);   // clamp idle lanes
  const int e      = blockIdx.x * 16 + (threadIdx.x >> 4);

  const float LOG2E = 1.4426950408889634f;
  // gate order i,f,g,o: sigmoid gates prescaled by -log2e (A=exp2 -> e^-x),
  // tanh gate by +2log2e (E=exp2 -> e^{2x}).
  const float sc[4] = { -LOG2E, -LOG2E, 2.0f * LOG2E, -LOG2E };

  float  wi1s[4];
  float2 b1p[4], b2p[4];             // {bias, 0} const accumulator inits
  float2 wh1p[4][HP], wi2p[4][HP], wh2p[4][HP];
  #pragma unroll
  for (int q = 0; q < 4; ++q) {
    const int   row = q * H + k;
    const float s   = sc[q];
    wi1s[q] = w_ih1[row] * s;                 // w_ih1 is [48,1]
    b1p[q]  = make_float2((b_ih1[row] + b_hh1[row]) * s, 0.0f);
    b2p[q]  = make_float2((b_ih2[row] + b_hh2[row]) * s, 0.0f);
    #pragma unroll
    for (int m = 0; m < HP; ++m) {
      wh1p[q][m] = make_float2(w_hh1[row * H + 2*m] * s, w_hh1[row * H + 2*m + 1] * s);
      wi2p[q][m] = make_float2(w_ih2[row * H + 2*m] * s, w_ih2[row * H + 2*m + 1] * s);
      wh2p[q][m] = make_float2(w_hh2[row * H + 2*m] * s, w_hh2[row * H + 2*m + 1] * s);
    }
  }
  const float wlin = (lane16 < H) ? w_lin[k] : 0.0f;    // idle lanes drop out of reduce
  const float blin = b_lin[0];

  float2 h1p[HP], h2p[HP];
  #pragma unroll
  for (int m = 0; m < HP; ++m) { h1p[m] = make_float2(0.f, 0.f); h2p[m] = make_float2(0.f, 0.f); }
  float c1 = 0.0f, c2 = 0.0f;

  const float* xrow = input + (size_t)e * T;
  float*       yrow = out   + (size_t)e * TT;

  const float TWO_LOG2E = 2.885390081777927f;

  auto step = [&](float x) -> float {
    // ---- cell 1 gate dots (bias pre-loaded in accumulator)
    float g1[4];
    #pragma unroll
    for (int q = 0; q < 4; ++q) {
      float2 a = pk_fma(h1p[0], wh1p[q][0], b1p[q]);
      #pragma unroll
      for (int m = 1; m < HP; ++m) a = pk_fma(h1p[m], wh1p[q][m], a);
      g1[q] = fmaf(wi1s[q], x, a.x + a.y);
    }
    // ---- cell 1 activations, merged-rcp (2 rcp total)
    {
      const float Ai = fexp2(g1[0]);
      const float Af = fexp2(g1[1]);
      const float Eg = fexp2(g1[2]);
      const float Ao = fexp2(g1[3]);
      const float pi = 1.0f + Ai, pf = 1.0f + Af, pe = 1.0f + Eg, po = 1.0f + Ao;
      const float P  = pi * pe;
      const float num = fmaf(c1, P, (Eg - 1.0f) * pf);
      c1 = num * frcp(P * pf);
      const float Ec = fexp2(TWO_LOG2E * c1);
      // h1o computed below after cell2's h2-partials are issued
      // (kept here for dependency clarity; compiler schedules)
      const float h1o = (Ec - 1.0f) * frcp(po * (1.0f + Ec));

      // ---- cell 2: h2-dependent partial dots FIRST (independent of new h1)
      float2 a2[4];
      #pragma unroll
      for (int q = 0; q < 4; ++q) {
        float2 a = pk_fma(h2p[0], wh2p[q][0], b2p[q]);
        #pragma unroll
        for (int m = 1; m < HP; ++m) a = pk_fma(h2p[m], wh2p[q][m], a);
        a2[q] = a;
      }

      // ---- broadcast new h1 (DPP) — overlaps with a2 chains above
      h1p[0] = make_float2(BCAST(h1o, 0),  BCAST(h1o, 1));
      h1p[1] = make_float2(BCAST(h1o, 2),  BCAST(h1o, 3));
      h1p[2] = make_float2(BCAST(h1o, 4),  BCAST(h1o, 5));
      h1p[3] = make_float2(BCAST(h1o, 6),  BCAST(h1o, 7));
      h1p[4] = make_float2(BCAST(h1o, 8),  BCAST(h1o, 9));
      h1p[5] = make_float2(BCAST(h1o, 10), BCAST(h1o, 11));

      // ---- cell 2: h1-dependent part
      float g2[4];
      #pragma unroll
      for (int q = 0; q < 4; ++q) {
        float2 a = a2[q];
        #pragma unroll
        for (int m = 0; m < HP; ++m) a = pk_fma(h1p[m], wi2p[q][m], a);
        g2[q] = a.x + a.y;
      }
      // ---- cell 2 activations, merged-rcp
      const float Ai2 = fexp2(g2[0]);
      const float Af2 = fexp2(g2[1]);
      const float Eg2 = fexp2(g2[2]);
      const float Ao2 = fexp2(g2[3]);
      const float pi2 = 1.0f + Ai2, pf2 = 1.0f + Af2, pe2 = 1.0f + Eg2, po2 = 1.0f + Ao2;
      const float P2  = pi2 * pe2;
      const float num2 = fmaf(c2, P2, (Eg2 - 1.0f) * pf2);
      c2 = num2 * frcp(P2 * pf2);
      const float Ec2 = fexp2(TWO_LOG2E * c2);
      const float h2o = (Ec2 - 1.0f) * frcp(po2 * (1.0f + Ec2));

      // ---- y reduce (butterfly over 16-lane group) — independent of h2 bcast
      float p = wlin * h2o;
      p += DPPMV(p, 0xB1);   // quad_perm [1,0,3,2]  (xor 1)
      p += DPPMV(p, 0x4E);   // quad_perm [2,3,0,1]  (xor 2)
      p += DPPMV(p, 0x104);  // row_shl:4
      p += DPPMV(p, 0x108);  // row_shl:8 -> lane 0 has full sum

      // ---- broadcast new h2
      h2p[0] = make_float2(BCAST(h2o, 0),  BCAST(h2o, 1));
      h2p[1] = make_float2(BCAST(h2o, 2),  BCAST(h2o, 3));
      h2p[2] = make_float2(BCAST(h2o, 4),  BCAST(h2o, 5));
      h2p[3] = make_float2(BCAST(h2o, 6),  BCAST(h2o, 7));
      h2p[4] = make_float2(BCAST(h2o, 8),  BCAST(h2o, 9));
      h2p[5] = make_float2(BCAST(h2o, 10), BCAST(h2o, 11));

      return p + blin;
    }
  };

  for (int tb = 0; tb < T; tb += 4) {
    const float4 xv = *reinterpret_cast<const float4*>(xrow + tb);
    float y0 = step(xv.x);
    float y1 = step(xv.y);
    float y2 = step(xv.z);
    float y3 = step(xv.w);
    if (lane16 == 0)
      *reinterpret_cast<float4*>(yrow + tb) = make_float4(y0, y1, y2, y3);
  }

  const float xl = xrow[T - 1];
  for (int tb = T; tb < TT; tb += 4) {
    float y0 = step(xl);
    float y1 = step(xl);
    float y2 = step(xl);
    float y3 = step(xl);
    if (lane16 == 0)
      *reinterpret_cast<float4*>(yrow + tb) = make_float4(y0, y1, y2, y3);
  }
}

extern "C" void kernel_launch(void* const* d_in, const int* in_sizes, int n_in,
                              void* d_out, int out_size, void* d_ws, size_t ws_size,
                              hipStream_t stream) {
  const float* input = (const float*)d_in[0];
  const float* w_ih1 = (const float*)d_in[2];
  const float* w_hh1 = (const float*)d_in[3];
  const float* b_ih1 = (const float*)d_in[4];
  const float* b_hh1 = (const float*)d_in[5];
  const float* w_ih2 = (const float*)d_in[6];
  const float* w_hh2 = (const float*)d_in[7];
  const float* b_ih2 = (const float*)d_in[8];
  const float* b_hh2 = (const float*)d_in[9];
  const float* w_lin = (const float*)d_in[10];
  const float* b_lin = (const float*)d_in[11];
  float* out = (float*)d_out;

  dim3 grid(B / 16);
  dim3 block(256);
  hipLaunchKernelGGL(lstm_seq_kernel, grid, block, 0, stream,
                     input, w_ih1, w_hh1, b_ih1, b_hh1,
                     w_ih2, w_hh2, b_ih2, b_hh2, w_lin, b_lin, out);
}

// Round 4
// 739.217 us; speedup vs baseline: 1.4851x; 1.0545x over previous
//
#include <hip/hip_runtime.h>

// 2-layer LSTM (H=12), B=8192, T=1024 + 64 free-running steps.
// 16 lanes per element; lane k owns hidden unit k (both cells).
// Recurrent dot products via v_dot2_f32_f16: h and recurrent weights in f16
// (packed half2), accumulation/cell-state/activations/output head in f32.
// Cross-lane traffic via DPP only (zero LDS). Activations use merged-rcp
// algebra (2 rcp/cell). Weights prescaled by +-log2e so exp2 args are ready;
// biases ride as the dot2 accumulator init.

constexpr int H   = 12;
constexpr int T   = 1024;
constexpr int FUT = 64;
constexpr int TT  = T + FUT;   // 1088
constexpr int B   = 8192;
constexpr int HP  = H / 2;     // 6 packed j-pairs

using half2_t = __attribute__((ext_vector_type(2))) _Float16;

// DPP: row_newbcast:J = 0x150+J (broadcast lane J within each 16-lane row)
#define BCASTI(v, J) __builtin_amdgcn_mov_dpp((v), 0x150 + (J), 0xF, 0xF, false)
// generic f32 DPP move with bound_ctrl=1 (out-of-range reads 0)
#define DPPMV(v, C) __int_as_float(__builtin_amdgcn_mov_dpp(__float_as_int(v), (C), 0xF, 0xF, true))
// lane i <- lane i+1 within the 16-lane row (row_shl:1; direction HW-verified
// by the passing R2/R3 butterfly which used 0x104/0x108 the same way)
#define SHL1I(v) __builtin_amdgcn_mov_dpp((v), 0x101, 0xF, 0xF, true)

static __device__ __forceinline__ float fdot2(int hp, int wp, float c) {
#if __has_builtin(__builtin_amdgcn_fdot2)
  return __builtin_amdgcn_fdot2(__builtin_bit_cast(half2_t, hp),
                                __builtin_bit_cast(half2_t, wp), c, false);
#else
  float d;
  asm("v_dot2_f32_f16 %0, %1, %2, %3" : "=v"(d) : "v"(hp), "v"(wp), "v"(c));
  return d;
#endif
}

static __device__ __forceinline__ int pack_f16(float a, float b) {
  unsigned short ua = __builtin_bit_cast(unsigned short, (_Float16)a);
  unsigned short ub = __builtin_bit_cast(unsigned short, (_Float16)b);
  return (int)ua | ((int)ub << 16);
}

static __device__ __forceinline__ float fexp2(float x) {
  return __builtin_amdgcn_exp2f(x);
}
static __device__ __forceinline__ float frcp(float x) {
  return __builtin_amdgcn_rcpf(x);
}

__global__ __launch_bounds__(256, 2) void lstm_seq_kernel(
    const float* __restrict__ input,
    const float* __restrict__ w_ih1, const float* __restrict__ w_hh1,
    const float* __restrict__ b_ih1, const float* __restrict__ b_hh1,
    const float* __restrict__ w_ih2, const float* __restrict__ w_hh2,
    const float* __restrict__ b_ih2, const float* __restrict__ b_hh2,
    const float* __restrict__ w_lin, const float* __restrict__ b_lin,
    float* __restrict__ out)
{
  const int lane16 = threadIdx.x & 15;
  const int k      = (lane16 < H) ? lane16 : (H - 1);   // clamp idle lanes
  const int e      = blockIdx.x * 16 + (threadIdx.x >> 4);

  const float LOG2E = 1.4426950408889634f;
  // gate order i,f,g,o: sigmoid gates prescaled by -log2e (A=exp2 -> e^-x),
  // tanh gate by +2log2e (E=exp2 -> e^{2x}).
  const float sc[4] = { -LOG2E, -LOG2E, 2.0f * LOG2E, -LOG2E };

  float wi1s[4], b1s[4], b2s[4];
  int   wh1h[4][HP], wi2h[4][HP], wh2h[4][HP];   // packed f16 pairs (prescaled)
  #pragma unroll
  for (int q = 0; q < 4; ++q) {
    const int   row = q * H + k;
    const float s   = sc[q];
    wi1s[q] = w_ih1[row] * s;                 // w_ih1 is [48,1], x path stays f32
    b1s[q]  = (b_ih1[row] + b_hh1[row]) * s;
    b2s[q]  = (b_ih2[row] + b_hh2[row]) * s;
    #pragma unroll
    for (int m = 0; m < HP; ++m) {
      wh1h[q][m] = pack_f16(w_hh1[row * H + 2*m] * s, w_hh1[row * H + 2*m + 1] * s);
      wi2h[q][m] = pack_f16(w_ih2[row * H + 2*m] * s, w_ih2[row * H + 2*m + 1] * s);
      wh2h[q][m] = pack_f16(w_hh2[row * H + 2*m] * s, w_hh2[row * H + 2*m + 1] * s);
    }
  }
  const float wlin = (lane16 < H) ? w_lin[k] : 0.0f;    // idle lanes drop out of reduce
  const float blin = b_lin[0];

  int h1h[HP], h2h[HP];                 // packed f16 hidden state (all lanes)
  #pragma unroll
  for (int m = 0; m < HP; ++m) { h1h[m] = 0; h2h[m] = 0; }
  float c1 = 0.0f, c2 = 0.0f;

  const float* xrow = input + (size_t)e * T;
  float*       yrow = out   + (size_t)e * TT;

  const float TWO_LOG2E = 2.885390081777927f;

  auto step = [&](float x) -> float {
    // ---- cell 1 gate dots (bias as dot2 accumulator init)
    float g1[4];
    #pragma unroll
    for (int q = 0; q < 4; ++q) {
      float a = b1s[q];
      #pragma unroll
      for (int m = 0; m < HP; ++m) a = fdot2(h1h[m], wh1h[q][m], a);
      g1[q] = fmaf(wi1s[q], x, a);
    }
    // ---- cell 1 activations, merged-rcp (2 rcp total)
    const float Ai = fexp2(g1[0]);
    const float Af = fexp2(g1[1]);
    const float Eg = fexp2(g1[2]);
    const float Ao = fexp2(g1[3]);
    const float pf = 1.0f + Af;
    const float P  = (1.0f + Ai) * (1.0f + Eg);
    c1 = fmaf(c1, P, (Eg - 1.0f) * pf) * frcp(P * pf);
    const float Ec = fexp2(TWO_LOG2E * c1);
    const float h1o = (Ec - 1.0f) * frcp((1.0f + Ao) * (1.0f + Ec));

    // ---- cell 2: h2-dependent partial dots FIRST (independent of new h1)
    float a2[4];
    #pragma unroll
    for (int q = 0; q < 4; ++q) {
      float a = b2s[q];
      #pragma unroll
      for (int m = 0; m < HP; ++m) a = fdot2(h2h[m], wh2h[q][m], a);
      a2[q] = a;
    }

    // ---- pack + broadcast new h1 (9 ops: cvt, dpp-neighbor, fuse, 6 bcast)
    {
      const int hl = (int)__builtin_bit_cast(unsigned short, (_Float16)h1o);
      const int hr = SHL1I(hl);                  // lane k <- lane k+1
      const int pr = (hr << 16) | hl;            // {h[k] lo, h[k+1] hi}
      h1h[0] = BCASTI(pr, 0);  h1h[1] = BCASTI(pr, 2);  h1h[2] = BCASTI(pr, 4);
      h1h[3] = BCASTI(pr, 6);  h1h[4] = BCASTI(pr, 8);  h1h[5] = BCASTI(pr, 10);
    }

    // ---- cell 2: h1-dependent part
    float g2[4];
    #pragma unroll
    for (int q = 0; q < 4; ++q) {
      float a = a2[q];
      #pragma unroll
      for (int m = 0; m < HP; ++m) a = fdot2(h1h[m], wi2h[q][m], a);
      g2[q] = a;
    }
    // ---- cell 2 activations, merged-rcp
    const float Ai2 = fexp2(g2[0]);
    const float Af2 = fexp2(g2[1]);
    const float Eg2 = fexp2(g2[2]);
    const float Ao2 = fexp2(g2[3]);
    const float pf2 = 1.0f + Af2;
    const float P2  = (1.0f + Ai2) * (1.0f + Eg2);
    c2 = fmaf(c2, P2, (Eg2 - 1.0f) * pf2) * frcp(P2 * pf2);
    const float Ec2 = fexp2(TWO_LOG2E * c2);
    const float h2o = (Ec2 - 1.0f) * frcp((1.0f + Ao2) * (1.0f + Ec2));

    // ---- y reduce on f32 h2o (butterfly over 16-lane group)
    float p = wlin * h2o;
    p += DPPMV(p, 0xB1);   // quad_perm [1,0,3,2]  (xor 1)
    p += DPPMV(p, 0x4E);   // quad_perm [2,3,0,1]  (xor 2)
    p += DPPMV(p, 0x104);  // row_shl:4
    p += DPPMV(p, 0x108);  // row_shl:8 -> lane 0 has full sum

    // ---- pack + broadcast new h2
    {
      const int hl = (int)__builtin_bit_cast(unsigned short, (_Float16)h2o);
      const int hr = SHL1I(hl);
      const int pr = (hr << 16) | hl;
      h2h[0] = BCASTI(pr, 0);  h2h[1] = BCASTI(pr, 2);  h2h[2] = BCASTI(pr, 4);
      h2h[3] = BCASTI(pr, 6);  h2h[4] = BCASTI(pr, 8);  h2h[5] = BCASTI(pr, 10);
    }

    return p + blin;
  };

  for (int tb = 0; tb < T; tb += 4) {
    const float4 xv = *reinterpret_cast<const float4*>(xrow + tb);
    float y0 = step(xv.x);
    float y1 = step(xv.y);
    float y2 = step(xv.z);
    float y3 = step(xv.w);
    if (lane16 == 0)
      *reinterpret_cast<float4*>(yrow + tb) = make_float4(y0, y1, y2, y3);
  }

  const float xl = xrow[T - 1];
  for (int tb = T; tb < TT; tb += 4) {
    float y0 = step(xl);
    float y1 = step(xl);
    float y2 = step(xl);
    float y3 = step(xl);
    if (lane16 == 0)
      *reinterpret_cast<float4*>(yrow + tb) = make_float4(y0, y1, y2, y3);
  }
}

extern "C" void kernel_launch(void* const* d_in, const int* in_sizes, int n_in,
                              void* d_out, int out_size, void* d_ws, size_t ws_size,
                              hipStream_t stream) {
  const float* input = (const float*)d_in[0];
  const float* w_ih1 = (const float*)d_in[2];
  const float* w_hh1 = (const float*)d_in[3];
  const float* b_ih1 = (const float*)d_in[4];
  const float* b_hh1 = (const float*)d_in[5];
  const float* w_ih2 = (const float*)d_in[6];
  const float* w_hh2 = (const float*)d_in[7];
  const float* b_ih2 = (const float*)d_in[8];
  const float* b_hh2 = (const float*)d_in[9];
  const float* w_lin = (const float*)d_in[10];
  const float* b_lin = (const float*)d_in[11];
  float* out = (float*)d_out;

  dim3 grid(B / 16);
  dim3 block(256);
  hipLaunchKernelGGL(lstm_seq_kernel, grid, block, 0, stream,
                     input, w_ih1, w_hh1, b_ih1, b_hh1,
                     w_ih2, w_hh2, b_ih2, b_hh2, w_lin, b_lin, out);
}

// Round 5
// 573.604 us; speedup vs baseline: 1.9138x; 1.2887x over previous
//
#include <hip/hip_runtime.h>

// 2-layer LSTM (H=12), B=8192, T=1024 + 64 free-running steps.
// MFMA formulation: block = 4 waves = 16 batch elements.
//   Wave w owns units {3w,3w+1,3w+2}. Per step, per cell, ONE
//   v_mfma_f32_16x16x32_f16 computes its 12 gate rows x 16 elements:
//     cell1: A1[16x32] = permuted rows of w_hh1 (K=12 used), B = h1(t-1)
//     cell2: A2[16x32] = [w_ih2 | w_hh2] rows    (K=24 used), B = [h1(t);h2(t-1)]
//   Row permutation row=4*unit_offset+gate makes D give each lane all 4 gates
//   of one (unit, element) pair -> activations stay fully lane-dense.
//   Bias = MFMA C operand. x-term: 4 f32 fma. y = w_lin . h2 rides as D-row 15
//   of wave3's cell2 MFMA (one step delayed: cell2's B carries h2(t-1)).
// h exchanged cross-wave via double-buffered LDS (f16) + 2 barriers/step.
// LDS zero-initialized once: all junk-read slots stay finite (0 * junk in the
// MFMA would NaN-poison if junk were NaN).
// Assumed fragment maps (gfx950, verified bf16, dtype-independent):
//   A[m = lane&15][k = 8*(lane>>4)+j],  B[k = 8*(lane>>4)+j][n = lane&15],
//   D[row = 4*(lane>>4)+reg][col = lane&15].

typedef _Float16 v8h  __attribute__((ext_vector_type(8)));
typedef _Float16 v4h  __attribute__((ext_vector_type(4)));
typedef float    v4f  __attribute__((ext_vector_type(4)));

constexpr int H   = 12;
constexpr int T   = 1024;
constexpr int FUT = 64;
constexpr int TT  = T + FUT;   // 1088
constexpr int B   = 8192;

static __device__ __forceinline__ float fexp2(float x){ return __builtin_amdgcn_exp2f(x); }
static __device__ __forceinline__ float frcp (float x){ return __builtin_amdgcn_rcpf(x); }

__global__ __launch_bounds__(256, 2) void lstm_mfma_kernel(
    const float* __restrict__ input,
    const float* __restrict__ w_ih1, const float* __restrict__ w_hh1,
    const float* __restrict__ b_ih1, const float* __restrict__ b_hh1,
    const float* __restrict__ w_ih2, const float* __restrict__ w_hh2,
    const float* __restrict__ b_ih2, const float* __restrict__ b_hh2,
    const float* __restrict__ w_lin, const float* __restrict__ b_lin,
    float* __restrict__ out)
{
  const int tid  = threadIdx.x;
  const int w    = tid >> 6;        // wave id 0..3 -> units 3w..3w+2
  const int lane = tid & 63;
  const int g    = lane >> 4;       // k-slice group / D-row group
  const int n    = lane & 15;       // element column
  const int e0   = blockIdx.x * 16;

  const float L2E = 1.4426950408889634f;
  const float sc[4] = { -L2E, -L2E, 2.0f * L2E, -L2E };  // i,f,g,o prescale
  const float TWO_L2E = 2.885390081777927f;

  // ---------------- A fragments (static, prescaled, zero-padded) ----------
  // Wave-local row m (= lane&15): m<12: gate q = m&3, unit u = 3w + (m>>2).
  v8h A1 = {0,0,0,0,0,0,0,0}, A2 = {0,0,0,0,0,0,0,0};
  {
    const int m = lane & 15;
    if (m < 12) {
      const int q = m & 3, u = 3 * w + (m >> 2);
      const float s = sc[q];
      const int grow = (q * 12 + u);
      #pragma unroll
      for (int j = 0; j < 8; ++j) {
        const int kk = 8 * g + j;
        if (kk < 12) {
          A1[j] = (_Float16)(s * w_hh1[grow * 12 + kk]);
          A2[j] = (_Float16)(s * w_ih2[grow * 12 + kk]);
        } else if (kk < 24) {
          A2[j] = (_Float16)(s * w_hh2[grow * 12 + (kk - 12)]);
        }
      }
    } else if (m == 15 && w == 3) {
      // y-row: w_lin against the h2 half of cell2's B (K slots 12..23)
      #pragma unroll
      for (int j = 0; j < 8; ++j) {
        const int kk = 8 * g + j;
        if (kk >= 12 && kk < 24) A2[j] = (_Float16)w_lin[kk - 12];
      }
    }
  }

  // ---------------- C bias fragments + x weights (D rows 4g+r) ------------
  v4f C1 = {0,0,0,0}, C2 = {0,0,0,0};
  float wi1s[4] = {0,0,0,0};
  const int uD = 3 * w + g;          // this lane's unit (valid when g<3)
  if (g < 3) {
    #pragma unroll
    for (int r = 0; r < 4; ++r) {
      C1[r]   = sc[r] * (b_ih1[r * 12 + uD] + b_hh1[r * 12 + uD]);
      C2[r]   = sc[r] * (b_ih2[r * 12 + uD] + b_hh2[r * 12 + uD]);
      wi1s[r] = sc[r] * w_ih1[r * 12 + uD];
    }
  }
  const float blin = b_lin[0];

  // ---------------- LDS: double-buffered f16 h1/h2 ------------------------
  // halves: H1[p][n][16] at p*256 + n*16 + u ; H2 same +512 ; pad [1024,1056)
  __shared__ _Float16 hb[1056];
  for (int i = tid; i < 1056; i += 256) hb[i] = (_Float16)0.0f;  // finite junk
  __syncthreads();
  char* hbB = (char*)hb;

  // Per-parity byte offsets (pY = parity of h(t); pX = pY^1 = parity of h(t-1))
  int xoffA[2], yloA[2], yhiA[2], wh1A[2], wh2A[2];
  #pragma unroll
  for (int pY = 0; pY < 2; ++pY) {
    const int pX = pY ^ 1;
    xoffA[pY] = pX * 512 + n * 32 + g * 16;              // cell1 B: h1(t-1), b128
    const int b1 = pY * 512 + n * 32;                    // h1(t)
    const int b2 = 1024 + pX * 512 + n * 32;             // h2(t-1)
    int lo, hi;
    if      (g == 0) { lo = b1;      hi = b1 + 8;  }     // h1[0..7]
    else if (g == 1) { lo = b1 + 16; hi = b2;      }     // h1[8..11]+pad | h2[0..3]
    else if (g == 2) { lo = b2 + 8;  hi = b2 + 16; }     // h2[4..11]
    else             { lo = 2048;    hi = 2056;    }     // zeroed pad (k>=24)
    yloA[pY] = lo; yhiA[pY] = hi;
    wh1A[pY] = pY * 256 + n * 16 + uD;                   // half-index writes
    wh2A[pY] = 512 + pY * 256 + n * 16 + uD;
  }

  float c1 = 0.0f, c2 = 0.0f;
  const float* xrow = input + (size_t)(e0 + n) * T;
  float*       yrow = out   + (size_t)(e0 + n) * TT;     // used by w3/g3 lanes
  const bool   ylane = (w == 3) && (g == 3);
  const float  xl = xrow[T - 1];

  float yb0 = 0.f, yb1 = 0.f, yb2 = 0.f, yb3 = 0.f;

  // merged-rcp activation for one unit: gates gg[0..3] -> h (updates c)
  auto act = [&](float g0, float g1, float g2v, float g3, float& c) -> float {
    const float Ai = fexp2(g0);
    const float Af = fexp2(g1);
    const float Eg = fexp2(g2v);
    const float Ao = fexp2(g3);
    const float pf = 1.0f + Af;
    const float P  = (1.0f + Ai) * (1.0f + Eg);
    c = fmaf(c, P, (Eg - 1.0f) * pf) * frcp(P * pf);
    const float Ec = fexp2(TWO_L2E * c);
    return (Ec - 1.0f) * frcp((1.0f + Ao) * (1.0f + Ec));
  };

  auto substep = [&](float x, int pY) -> float {   // returns this step's y(t-1) raw
    // ---- cell 1: D1 = A1 * h1(t-1) + bias
    v8h X = *(const v8h*)(hbB + xoffA[pY]);
    v4f D1 = __builtin_amdgcn_mfma_f32_16x16x32_f16(A1, X, C1, 0, 0, 0);
    const float h1o = act(fmaf(wi1s[0], x, D1[0]), fmaf(wi1s[1], x, D1[1]),
                          fmaf(wi1s[2], x, D1[2]), fmaf(wi1s[3], x, D1[3]), c1);
    if (g < 3) hb[wh1A[pY]] = (_Float16)h1o;
    __syncthreads();

    // ---- cell 2: D2 = A2 * [h1(t); h2(t-1)] + bias
    v4h ylo = *(const v4h*)(hbB + yloA[pY]);
    v4h yhi = *(const v4h*)(hbB + yhiA[pY]);
    v8h Y;
    #pragma unroll
    for (int j = 0; j < 4; ++j) { Y[j] = ylo[j]; Y[4 + j] = yhi[j]; }
    v4f D2 = __builtin_amdgcn_mfma_f32_16x16x32_f16(A2, Y, C2, 0, 0, 0);
    const float yraw = D2[3];                       // w3/g3: y(t-1) pre-bias
    const float h2o = act(D2[0], D2[1], D2[2], D2[3], c2);
    if (g < 3) hb[wh2A[pY]] = (_Float16)h2o;
    __syncthreads();
    return yraw;
  };

  for (int tb = 0; tb < TT; tb += 4) {
    float4 xv;
    if (tb < T) xv = *reinterpret_cast<const float4*>(xrow + tb);
    else        xv = make_float4(xl, xl, xl, xl);

    // t = tb   (pY=0): MFMA2 yields y(tb-1) -> slot 3; flush chunk
    yb3 = substep(xv.x, 0) + blin;
    if (tb > 0 && ylane)
      *reinterpret_cast<float4*>(yrow + tb - 4) = make_float4(yb0, yb1, yb2, yb3);
    yb0 = substep(xv.y, 1) + blin;   // y(tb)
    yb1 = substep(xv.z, 0) + blin;   // y(tb+1)
    yb2 = substep(xv.w, 1) + blin;   // y(tb+2)
  }

  // Epilogue: y(TT-1) = w_lin . h2(TT-1). Use a cell2 MFMA with pY = TT&1 = 0:
  // its h2 part reads parity 1 = (TT-1)&1 (fresh h2); h1 part is stale/finite
  // and the y-row's A2 is zero on k<12, so it doesn't matter.
  {
    v4h ylo = *(const v4h*)(hbB + yloA[0]);
    v4h yhi = *(const v4h*)(hbB + yhiA[0]);
    v8h Y;
    #pragma unroll
    for (int j = 0; j < 4; ++j) { Y[j] = ylo[j]; Y[4 + j] = yhi[j]; }
    v4f D2 = __builtin_amdgcn_mfma_f32_16x16x32_f16(A2, Y, C2, 0, 0, 0);
    yb3 = D2[3] + blin;
    if (ylane)
      *reinterpret_cast<float4*>(yrow + TT - 4) = make_float4(yb0, yb1, yb2, yb3);
  }
}

extern "C" void kernel_launch(void* const* d_in, const int* in_sizes, int n_in,
                              void* d_out, int out_size, void* d_ws, size_t ws_size,
                              hipStream_t stream) {
  const float* input = (const float*)d_in[0];
  const float* w_ih1 = (const float*)d_in[2];
  const float* w_hh1 = (const float*)d_in[3];
  const float* b_ih1 = (const float*)d_in[4];
  const float* b_hh1 = (const float*)d_in[5];
  const float* w_ih2 = (const float*)d_in[6];
  const float* w_hh2 = (const float*)d_in[7];
  const float* b_ih2 = (const float*)d_in[8];
  const float* b_hh2 = (const float*)d_in[9];
  const float* w_lin = (const float*)d_in[10];
  const float* b_lin = (const float*)d_in[11];
  float* out = (float*)d_out;

  dim3 grid(B / 16);   // 512 blocks x 4 waves = 2048 waves = 2/SIMD
  dim3 block(256);
  hipLaunchKernelGGL(lstm_mfma_kernel, grid, block, 0, stream,
                     input, w_ih1, w_hh1, b_ih1, b_hh1,
                     w_ih2, w_hh2, b_ih2, b_hh2, w_lin, b_lin, out);
}

// Round 6
// 535.589 us; speedup vs baseline: 2.0497x; 1.0710x over previous
//
#include <hip/hip_runtime.h>

// 2-layer LSTM (H=12), B=8192, T=1024 + 64 free-running steps.
// MFMA formulation: block = 4 waves = 16 batch elements; wave w owns units
// {3w,3w+1,3w+2}; one v_mfma_f32_16x16x32_f16 per cell per step.
// R6: ONE barrier per step + fused 48B/element LDS records:
//   region[p] (832 B): elem n at n*48 = { h1(parity p)[12 f16] | h2(parity p^1)[12 f16] }
//   cell1(t): read region[p^1] (h1(t-1); h2 slots junk but A1-zeroed), write h1(t)->region[p]
//   BARRIER
//   cell2(t): ONE b128 read region[p] = [h1(t) | h2(t-1)], write h2(t)->region[p^1]
// Parity argument shows every cross-wave RAW/WAR pair is separated by exactly
// one barrier. Junk slots only ever multiply zero A-entries and stay finite
// (LDS zero-initialized once).
// Stride 48 B -> b128 start banks (12n+4g)%32 uniform over 8 banks: no 4-way
// conflicts (was n*32 -> 3.6e7 conflict cycles in R5).
// Fragment maps (gfx950, dtype-independent, HW-verified):
//   A[m=lane&15][k=8*(lane>>4)+j], B[k=8*(lane>>4)+j][n=lane&15],
//   D[row=4*(lane>>4)+reg][col=lane&15].

typedef _Float16 v8h  __attribute__((ext_vector_type(8)));
typedef float    v4f  __attribute__((ext_vector_type(4)));

constexpr int H   = 12;
constexpr int T   = 1024;
constexpr int FUT = 64;
constexpr int TT  = T + FUT;   // 1088
constexpr int B   = 8192;

static __device__ __forceinline__ float fexp2(float x){ return __builtin_amdgcn_exp2f(x); }
static __device__ __forceinline__ float frcp (float x){ return __builtin_amdgcn_rcpf(x); }

__global__ __launch_bounds__(256, 2) void lstm_mfma_kernel(
    const float* __restrict__ input,
    const float* __restrict__ w_ih1, const float* __restrict__ w_hh1,
    const float* __restrict__ b_ih1, const float* __restrict__ b_hh1,
    const float* __restrict__ w_ih2, const float* __restrict__ w_hh2,
    const float* __restrict__ b_ih2, const float* __restrict__ b_hh2,
    const float* __restrict__ w_lin, const float* __restrict__ b_lin,
    float* __restrict__ out)
{
  const int tid  = threadIdx.x;
  const int w    = tid >> 6;        // wave id 0..3 -> units 3w..3w+2
  const int lane = tid & 63;
  const int g    = lane >> 4;       // k-slice group / D-row group
  const int n    = lane & 15;       // element column
  const int e0   = blockIdx.x * 16;

  const float L2E = 1.4426950408889634f;
  const float sc[4] = { -L2E, -L2E, 2.0f * L2E, -L2E };  // i,f,g,o prescale
  const float TWO_L2E = 2.885390081777927f;

  // ---------------- A fragments (static, prescaled, zero-padded) ----------
  v8h A1 = {0,0,0,0,0,0,0,0}, A2 = {0,0,0,0,0,0,0,0};
  {
    const int m = lane & 15;
    if (m < 12) {
      const int q = m & 3, u = 3 * w + (m >> 2);
      const float s = sc[q];
      const int grow = (q * 12 + u);
      #pragma unroll
      for (int j = 0; j < 8; ++j) {
        const int kk = 8 * g + j;
        if (kk < 12) {
          A1[j] = (_Float16)(s * w_hh1[grow * 12 + kk]);
          A2[j] = (_Float16)(s * w_ih2[grow * 12 + kk]);
        } else if (kk < 24) {
          A2[j] = (_Float16)(s * w_hh2[grow * 12 + (kk - 12)]);
        }
      }
    } else if (m == 15 && w == 3) {
      // y-row: w_lin against the h2 half (K slots 12..23)
      #pragma unroll
      for (int j = 0; j < 8; ++j) {
        const int kk = 8 * g + j;
        if (kk >= 12 && kk < 24) A2[j] = (_Float16)w_lin[kk - 12];
      }
    }
  }

  // ---------------- C bias fragments + x weights (D rows 4g+r) ------------
  v4f C1 = {0,0,0,0}, C2 = {0,0,0,0};
  float wi1s[4] = {0,0,0,0};
  const int uD = 3 * w + g;          // this lane's unit (valid when g<3)
  if (g < 3) {
    #pragma unroll
    for (int r = 0; r < 4; ++r) {
      C1[r]   = sc[r] * (b_ih1[r * 12 + uD] + b_hh1[r * 12 + uD]);
      C2[r]   = sc[r] * (b_ih2[r * 12 + uD] + b_hh2[r * 12 + uD]);
      wi1s[r] = sc[r] * w_ih1[r * 12 + uD];
    }
  }
  const float blin = b_lin[0];

  // ---------------- LDS: two 832-B parity regions of 48-B element records --
  __shared__ _Float16 hb[832];       // 1664 bytes
  for (int i = tid; i < 832; i += 256) hb[i] = (_Float16)0.0f;  // finite junk
  __syncthreads();
  char* hbB = (char*)hb;

  // Byte/half offsets per parity p = t&1:
  int c1r[2], c2r[2], w1h[2], w2h[2];
  #pragma unroll
  for (int p = 0; p < 2; ++p) {
    c1r[p] = (p ^ 1) * 832 + n * 48 + g * 16;            // cell1 B (b128)
    c2r[p] = p * 832 + n * 48 + g * 16;                  // cell2 B (b128)
    w1h[p] = p * 416 + n * 24 + uD;                      // h1(t) write (f16 idx)
    w2h[p] = (p ^ 1) * 416 + n * 24 + 12 + uD;           // h2(t) write
  }

  float c1 = 0.0f, c2 = 0.0f;
  const float* xrow = input + (size_t)(e0 + n) * T;
  float*       yrow = out   + (size_t)(e0 + n) * TT;     // used by w3/g3 lanes
  const bool   ylane = (w == 3) && (g == 3);
  const float  xl = xrow[T - 1];

  float yb0 = 0.f, yb1 = 0.f, yb2 = 0.f, yb3 = 0.f;

  auto act = [&](float g0, float g1, float g2v, float g3, float& c) -> float {
    const float Ai = fexp2(g0);
    const float Af = fexp2(g1);
    const float Eg = fexp2(g2v);
    const float Ao = fexp2(g3);
    const float pf = 1.0f + Af;
    const float P  = (1.0f + Ai) * (1.0f + Eg);
    c = fmaf(c, P, (Eg - 1.0f) * pf) * frcp(P * pf);
    const float Ec = fexp2(TWO_L2E * c);
    return (Ec - 1.0f) * frcp((1.0f + Ao) * (1.0f + Ec));
  };

  auto substep = [&](float x, int p) -> float {   // returns y(t-1) raw (w3/g3)
    // ---- cell 1: D1 = A1 * h1(t-1) + bias   (h2 slots junk * 0)
    v8h X = *(const v8h*)(hbB + c1r[p]);
    v4f D1 = __builtin_amdgcn_mfma_f32_16x16x32_f16(A1, X, C1, 0, 0, 0);
    const float h1o = act(fmaf(wi1s[0], x, D1[0]), fmaf(wi1s[1], x, D1[1]),
                          fmaf(wi1s[2], x, D1[2]), fmaf(wi1s[3], x, D1[3]), c1);
    if (g < 3) hb[w1h[p]] = (_Float16)h1o;
    __syncthreads();                                   // the ONLY barrier/step

    // ---- cell 2: D2 = A2 * [h1(t); h2(t-1)] + bias (one b128)
    v8h Y = *(const v8h*)(hbB + c2r[p]);
    v4f D2 = __builtin_amdgcn_mfma_f32_16x16x32_f16(A2, Y, C2, 0, 0, 0);
    const float yraw = D2[3];
    const float h2o = act(D2[0], D2[1], D2[2], D2[3], c2);
    if (g < 3) hb[w2h[p]] = (_Float16)h2o;
    return yraw;
  };

  for (int tb = 0; tb < TT; tb += 4) {
    float4 xv;
    if (tb < T) xv = *reinterpret_cast<const float4*>(xrow + tb);
    else        xv = make_float4(xl, xl, xl, xl);

    yb3 = substep(xv.x, 0) + blin;                 // yields y(tb-1)
    if (tb > 0 && ylane)
      *reinterpret_cast<float4*>(yrow + tb - 4) = make_float4(yb0, yb1, yb2, yb3);
    yb0 = substep(xv.y, 1) + blin;   // y(tb)
    yb1 = substep(xv.z, 0) + blin;   // y(tb+1)
    yb2 = substep(xv.w, 1) + blin;   // y(tb+2)
  }

  // Epilogue: y(TT-1) = w_lin . h2(TT-1). h2(1087) sits in region[0]+24
  // (written post-last-barrier -> need one barrier). h1 slots of region[0]
  // hold stale-but-finite h1(1086); y-row A2 is zero on k<12.
  __syncthreads();
  {
    v8h Y = *(const v8h*)(hbB + c2r[0]);
    v4f D2 = __builtin_amdgcn_mfma_f32_16x16x32_f16(A2, Y, C2, 0, 0, 0);
    yb3 = D2[3] + blin;
    if (ylane)
      *reinterpret_cast<float4*>(yrow + TT - 4) = make_float4(yb0, yb1, yb2, yb3);
  }
}

extern "C" void kernel_launch(void* const* d_in, const int* in_sizes, int n_in,
                              void* d_out, int out_size, void* d_ws, size_t ws_size,
                              hipStream_t stream) {
  const float* input = (const float*)d_in[0];
  const float* w_ih1 = (const float*)d_in[2];
  const float* w_hh1 = (const float*)d_in[3];
  const float* b_ih1 = (const float*)d_in[4];
  const float* b_hh1 = (const float*)d_in[5];
  const float* w_ih2 = (const float*)d_in[6];
  const float* w_hh2 = (const float*)d_in[7];
  const float* b_ih2 = (const float*)d_in[8];
  const float* b_hh2 = (const float*)d_in[9];
  const float* w_lin = (const float*)d_in[10];
  const float* b_lin = (const float*)d_in[11];
  float* out = (float*)d_out;

  dim3 grid(B / 16);   // 512 blocks x 4 waves = 2048 waves = 2/SIMD
  dim3 block(256);
  hipLaunchKernelGGL(lstm_mfma_kernel, grid, block, 0, stream,
                     input, w_ih1, w_hh1, b_ih1, b_hh1,
                     w_ih2, w_hh2, b_ih2, b_hh2, w_lin, b_lin, out);
}